// Round 1
// baseline (432.505 us; speedup 1.0000x reference)
//
#include <hip/hip_runtime.h>

// Problem geometry (fixed by reference: inputs (16, 4, 1024, 1024) fp32)
constexpr int NB = 16;
constexpr int NH = 1024;
constexpr int NW = 1024;

// Stencil tile: 128x32 per 256-thread block (16 outputs/thread)
constexpr int TX = 128;
constexpr int TY = 32;
constexpr int NPART = 1024;   // reduction partials in d_ws

// sT: T_prev tile, rows gy=y0-2..y0+33 (36), cols gx=x0-4..x0+131 (136 floats)
//     left halo widened 2->4 so x0-4 stays 16B-aligned for float4 loads.
constexpr int RA  = TY + 4;        // 36 rows
constexpr int CA  = TX + 8;        // 136 floats
constexpr int CA4 = CA / 4;        // 34 float4 per row
constexpr int STW = CA + 4;        // 140: pad keeps float4 alignment (560B rows), breaks pow2
// sN: T_new tile, rows gy=y0-1..y0+32 (34), same 136-wide cols, stride 140
constexpr int RB  = TY + 2;        // 34 rows
constexpr int SNW = 140;

// ---------------------------------------------------------------------------
// Kernel 1: per-block max(|u|,|v|) partials -> ws[0..NPART). No atomics, no
// memset needed: all NPART slots are plain-stored every call.
// u,v are the first 2*NH*NW floats of each batch (batch stride 4*NH*NW).
// ---------------------------------------------------------------------------
__global__ __launch_bounds__(256) void uvmax_kernel(const float4* __restrict__ in,
                                                    float* __restrict__ part) {
    const size_t n4 = (size_t)NB * 2 * NH * NW / 4;      // 8M float4
    size_t i0 = (size_t)blockIdx.x * blockDim.x + threadIdx.x;
    size_t stride = (size_t)gridDim.x * blockDim.x;
    float m = 0.0f;
    for (size_t i = i0; i < n4; i += stride) {
        size_t b   = i >> 19;                  // 2*NH*NW/4 = 2^19 f4 per batch
        size_t off = i & ((1u << 19) - 1);
        float4 x = in[(b << 20) + off];        // batch stride = 2^20 f4
        m = fmaxf(m, fmaxf(fmaxf(fabsf(x.x), fabsf(x.y)),
                           fmaxf(fabsf(x.z), fabsf(x.w))));
    }
    for (int o = 32; o > 0; o >>= 1) m = fmaxf(m, __shfl_down(m, o));
    __shared__ float sm[4];
    if ((threadIdx.x & 63) == 0) sm[threadIdx.x >> 6] = m;
    __syncthreads();
    if (threadIdx.x == 0)
        part[blockIdx.x] = fmaxf(fmaxf(sm[0], sm[1]), fmaxf(sm[2], sm[3]));
}

// ---------------------------------------------------------------------------
// Kernel 2: fused advection + Laplacian. Each block: reduce partials -> dt,
// stage T_prev (halo 2) in LDS, compute T_new (halo 1) in LDS with
// edge-replication via clamped-coordinate indexing, then 9-pt Laplacian.
// All in-bounds global traffic is aligned float4.
// Stencil LDS reads are aligned ds_read_b128 (conflict-free 16B-stride
// pattern) instead of scalar b32 at 16B lane stride (8-way conflicts).
// ---------------------------------------------------------------------------
__global__ __launch_bounds__(256) void step_kernel(const float* __restrict__ in,
                                                   const float* __restrict__ part,
                                                   float* __restrict__ out) {
    __shared__ float sT[RA * STW];
    __shared__ float sN[RB * SNW];
    __shared__ float sred[4];
    __shared__ float sdt;

    const int tid = threadIdx.x;

    // --- dt from the NPART partials (1 float4/thread, L2-resident) ---
    {
        float4 p = ((const float4*)part)[tid];            // 256*4 = 1024
        float m = fmaxf(fmaxf(p.x, p.y), fmaxf(p.z, p.w));
        for (int o = 32; o > 0; o >>= 1) m = fmaxf(m, __shfl_down(m, o));
        if ((tid & 63) == 0) sred[tid >> 6] = m;
        __syncthreads();
        if (tid == 0) {
            float mm = fmaxf(fmaxf(sred[0], sred[1]), fmaxf(sred[2], sred[3]));
            const float dx = 1.0f / 126.0f, dx2 = dx * dx;
            float dta = 0.5f * 0.1f * dx / mm;
            float dtd = 0.5f * (dx2 * dx2) / (dx2 + dx2);
            sdt = fminf(dta, dtd);
        }
        __syncthreads();
    }
    const float dt = sdt;

    const int b  = blockIdx.z;
    const int x0 = blockIdx.x * TX;
    const int y0 = blockIdx.y * TY;
    const size_t cs = (size_t)NH * NW;
    const float* Uc = in + (size_t)b * 4 * cs;
    const float* Vc = Uc + cs;
    const float* Tc = Uc + 2 * cs;
    const float* Rc = Uc + 3 * cs;

    const float dx    = 1.0f / 126.0f;
    const float dt_dx = dt / dx;             // fold /dx into one multiplier
    const float q_dx2 = 0.25f / (dx * dx);   // fold 0.25/dx^2

    // --- Phase A: stage T_prev, rows clamped in y; vector loads unless the
    //     float4 spans an x edge (only x-edge blocks take the scalar path) ---
    for (int idx = tid; idx < RA * CA4; idx += 256) {
        int j  = idx / CA4;
        int cc = idx - j * CA4;
        int gy  = min(max(y0 + j - 2, 0), NH - 1);
        int gxb = x0 - 4 + 4 * cc;
        float4 t4;
        if (gxb >= 0 && gxb + 3 < NW) {
            t4 = *(const float4*)&Tc[(size_t)gy * NW + gxb];
        } else {
            float* f = (float*)&t4;
            #pragma unroll
            for (int k = 0; k < 4; k++) {
                int cgx = min(max(gxb + k, 0), NW - 1);
                f[k] = Tc[(size_t)gy * NW + cgx];
            }
        }
        *(float4*)&sT[j * STW + 4 * cc] = t4;
    }
    __syncthreads();

    // --- Phase B: T_new on halo-1 grid (plus junk cols at the far pads,
    //     never read by Phase C). Halo points recomputed at CLAMPED coords
    //     -> correct edge replication of T_new.
    //     Interior path: 5 aligned b128 LDS reads (center, x-4, x+4, y-1, y+1)
    //     replace 20 conflicted scalar reads. Junk from the pad float4s
    //     (s[-4].w at cc=0, s[+4].x at cc=33) only reaches outputs Phase C
    //     never reads (positions 0..2 and 133..135), same as before. ---
    for (int idx = tid; idx < RB * CA4; idx += 256) {
        int ty = idx / CA4;
        int cc = idx - ty * CA4;
        int gy  = y0 + ty - 1;
        int cgy = min(max(gy, 0), NH - 1);
        int lj  = cgy - y0 + 2;              // in [1, 34]
        int gxb = x0 - 4 + 4 * cc;
        size_t rowo = (size_t)cgy * NW;
        float tn[4];
        if (gxb >= 0 && gxb + 3 < NW) {
            float4 u4 = *(const float4*)&Uc[rowo + gxb];
            float4 v4 = *(const float4*)&Vc[rowo + gxb];
            const float* s = &sT[lj * STW + 4 * cc];
            float4 cm = *(const float4*)(s - 4);     // only .w (= s[-1]) used
            float4 c4 = *(const float4*)(s);
            float4 cp = *(const float4*)(s + 4);     // only .x (= s[4]) used
            float4 up = *(const float4*)(s - STW);
            float4 dn = *(const float4*)(s + STW);
            float cx[6] = {cm.w, c4.x, c4.y, c4.z, c4.w, cp.x};
            float uu[4] = {u4.x, u4.y, u4.z, u4.w};
            float vv[4] = {v4.x, v4.y, v4.z, v4.w};
            float uq[4] = {up.x, up.y, up.z, up.w};
            float dq[4] = {dn.x, dn.y, dn.z, dn.w};
            #pragma unroll
            for (int k = 0; k < 4; k++) {
                float c = cx[k + 1];
                float selx = (uu[k] > 0.f) ? (c - cx[k])
                           : ((uu[k] < 0.f) ? (cx[k + 2] - c) : 0.f);
                float sely = (vv[k] > 0.f) ? (c - uq[k])
                           : ((vv[k] < 0.f) ? (dq[k] - c) : 0.f);
                tn[k] = c - dt_dx * (uu[k] * selx + vv[k] * sely);
            }
        } else {
            // scalar clamped path: only 1 float4 per row on the two x-edge
            // block columns takes this.
            #pragma unroll
            for (int k = 0; k < 4; k++) {
                int cgx = min(max(gxb + k, 0), NW - 1);
                float uu = Uc[rowo + cgx];
                float vv = Vc[rowo + cgx];
                int li = cgx - x0 + 4;       // index LDS by clamped coord
                const float* s = &sT[lj * STW + li];
                float c = s[0];
                float selx = (uu > 0.f) ? (c - s[-1])
                           : ((uu < 0.f) ? (s[1] - c) : 0.f);
                float sely = (vv > 0.f) ? (c - s[-STW])
                           : ((vv < 0.f) ? (s[STW] - c) : 0.f);
                tn[k] = c - dt_dx * (uu * selx + vv * sely);
            }
        }
        *(float4*)&sN[ty * SNW + 4 * cc] = make_float4(tn[0], tn[1], tn[2], tn[3]);
    }
    __syncthreads();

    // --- Phase C: 9-pt Laplacian of T_new + source, aligned float4 I/O.
    //     9 aligned b128 LDS reads (3 rows x {x-4, x, x+4}) replace ~18
    //     conflicted scalar reads. m*.w / p*.x are the +-1 neighbors. ---
    float* Ob = out + b * cs;
    for (int idx = tid; idx < TY * (TX / 4); idx += 256) {
        int ty = idx / (TX / 4);
        int cc = idx - ty * (TX / 4);
        int gy  = y0 + ty;
        int gxb = x0 + 4 * cc;
        const float* r0 = &sN[ty * SNW + 4 + 4 * cc];   // row gy-1
        const float* r1 = r0 + SNW;                     // row gy
        const float* r2 = r1 + SNW;                     // row gy+1
        float4 rq = *(const float4*)&Rc[(size_t)gy * NW + gxb];
        float4 m0 = *(const float4*)(r0 - 4);
        float4 a0 = *(const float4*)(r0);
        float4 p0 = *(const float4*)(r0 + 4);
        float4 m1 = *(const float4*)(r1 - 4);
        float4 a1 = *(const float4*)(r1);
        float4 p1 = *(const float4*)(r1 + 4);
        float4 m2 = *(const float4*)(r2 - 4);
        float4 a2 = *(const float4*)(r2);
        float4 p2 = *(const float4*)(r2 + 4);
        float X0[6] = {m0.w, a0.x, a0.y, a0.z, a0.w, p0.x};
        float X1[6] = {m1.w, a1.x, a1.y, a1.z, a1.w, p1.x};
        float X2[6] = {m2.w, a2.x, a2.y, a2.z, a2.w, p2.x};
        float rqv[4] = {rq.x, rq.y, rq.z, rq.w};
        float o[4];
        #pragma unroll
        for (int k = 0; k < 4; k++) {
            float lap = (        X0[k] + 2.f * X0[k + 1] +        X0[k + 2]
                        + 2.f * X1[k] - 12.f * X1[k + 1] + 2.f * X1[k + 2]
                        +       X2[k] + 2.f * X2[k + 1] +        X2[k + 2]) * q_dx2;
            o[k] = X1[k + 1] + dt * (lap + rqv[k]);
        }
        *(float4*)&Ob[(size_t)gy * NW + gxb] = make_float4(o[0], o[1], o[2], o[3]);
    }

    // dt scalar (last output element)
    if (b == 0 && blockIdx.x == 0 && blockIdx.y == 0 && tid == 0)
        out[(size_t)NB * cs] = dt;
}

extern "C" void kernel_launch(void* const* d_in, const int* in_sizes, int n_in,
                              void* d_out, int out_size, void* d_ws, size_t ws_size,
                              hipStream_t stream) {
    const float* in = (const float*)d_in[0];
    float* out = (float*)d_out;
    float* part = (float*)d_ws;   // NPART floats, fully overwritten each call

    uvmax_kernel<<<NPART, 256, 0, stream>>>((const float4*)in, part);

    dim3 grid(NW / TX, NH / TY, NB);   // (8, 32, 16)
    step_kernel<<<grid, 256, 0, stream>>>(in, part, out);
}

// Round 2
// 415.638 us; speedup vs baseline: 1.0406x; 1.0406x over previous
//
#include <hip/hip_runtime.h>

// Problem geometry (fixed by reference: inputs (16, 4, 1024, 1024) fp32)
constexpr int NB = 16;
constexpr int NH = 1024;
constexpr int NW = 1024;

// Stencil tile: 128x16 per 256-thread block (8 outputs/thread).
// Tile shrunk from 128x32 -> 128x16: LDS 40.3 KB -> 21.3 KB per block,
// co-residency 4 -> 7 blocks/CU (16 -> 28 waves/CU) for latency hiding.
constexpr int TX = 128;
constexpr int TY = 16;
constexpr int NPART = 1024;   // reduction partials in d_ws

// sT: T_prev tile, rows gy=y0-2..y0+TY+1 (TY+4), cols gx=x0-4..x0+131 (136)
//     left halo widened 2->4 so x0-4 stays 16B-aligned for float4 loads.
constexpr int RA  = TY + 4;        // 20 rows
constexpr int CA  = TX + 8;        // 136 floats
constexpr int CA4 = CA / 4;        // 34 float4 per row
constexpr int STW = CA + 4;        // 140: pad keeps float4 alignment (560B rows), breaks pow2
// sN: T_new tile, rows gy=y0-1..y0+TY (TY+2), same 136-wide cols, stride 140
constexpr int RB  = TY + 2;        // 18 rows
constexpr int SNW = 140;

// ---------------------------------------------------------------------------
// Kernel 1: per-block max(|u|,|v|) partials -> ws[0..NPART). No atomics, no
// memset needed: all NPART slots are plain-stored every call.
// u,v are the first 2*NH*NW floats of each batch (batch stride 4*NH*NW).
// ---------------------------------------------------------------------------
__global__ __launch_bounds__(256) void uvmax_kernel(const float4* __restrict__ in,
                                                    float* __restrict__ part) {
    const size_t n4 = (size_t)NB * 2 * NH * NW / 4;      // 8M float4
    size_t i0 = (size_t)blockIdx.x * blockDim.x + threadIdx.x;
    size_t stride = (size_t)gridDim.x * blockDim.x;
    float m = 0.0f;
    for (size_t i = i0; i < n4; i += stride) {
        size_t b   = i >> 19;                  // 2*NH*NW/4 = 2^19 f4 per batch
        size_t off = i & ((1u << 19) - 1);
        float4 x = in[(b << 20) + off];        // batch stride = 2^20 f4
        m = fmaxf(m, fmaxf(fmaxf(fabsf(x.x), fabsf(x.y)),
                           fmaxf(fabsf(x.z), fabsf(x.w))));
    }
    for (int o = 32; o > 0; o >>= 1) m = fmaxf(m, __shfl_down(m, o));
    __shared__ float sm[4];
    if ((threadIdx.x & 63) == 0) sm[threadIdx.x >> 6] = m;
    __syncthreads();
    if (threadIdx.x == 0)
        part[blockIdx.x] = fmaxf(fmaxf(sm[0], sm[1]), fmaxf(sm[2], sm[3]));
}

// ---------------------------------------------------------------------------
// Kernel 2: fused advection + Laplacian. Each block: reduce partials -> dt,
// stage T_prev (halo 2) in LDS, compute T_new (halo 1) in LDS with
// edge-replication via clamped-coordinate indexing, then 9-pt Laplacian.
// All in-bounds global traffic is aligned float4; stencil LDS reads are
// aligned ds_read_b128 (conflict-free 16B-stride pattern).
// ---------------------------------------------------------------------------
__global__ __launch_bounds__(256) void step_kernel(const float* __restrict__ in,
                                                   const float* __restrict__ part,
                                                   float* __restrict__ out) {
    __shared__ float sT[RA * STW];
    __shared__ float sN[RB * SNW];
    __shared__ float sred[4];
    __shared__ float sdt;

    const int tid = threadIdx.x;

    // --- dt from the NPART partials (1 float4/thread, L2-resident) ---
    {
        float4 p = ((const float4*)part)[tid];            // 256*4 = 1024
        float m = fmaxf(fmaxf(p.x, p.y), fmaxf(p.z, p.w));
        for (int o = 32; o > 0; o >>= 1) m = fmaxf(m, __shfl_down(m, o));
        if ((tid & 63) == 0) sred[tid >> 6] = m;
        __syncthreads();
        if (tid == 0) {
            float mm = fmaxf(fmaxf(sred[0], sred[1]), fmaxf(sred[2], sred[3]));
            const float dx = 1.0f / 126.0f, dx2 = dx * dx;
            float dta = 0.5f * 0.1f * dx / mm;
            float dtd = 0.5f * (dx2 * dx2) / (dx2 + dx2);
            sdt = fminf(dta, dtd);
        }
        __syncthreads();
    }
    const float dt = sdt;

    const int b  = blockIdx.z;
    const int x0 = blockIdx.x * TX;
    const int y0 = blockIdx.y * TY;
    const size_t cs = (size_t)NH * NW;
    const float* Uc = in + (size_t)b * 4 * cs;
    const float* Vc = Uc + cs;
    const float* Tc = Uc + 2 * cs;
    const float* Rc = Uc + 3 * cs;

    const float dx    = 1.0f / 126.0f;
    const float dt_dx = dt / dx;             // fold /dx into one multiplier
    const float q_dx2 = 0.25f / (dx * dx);   // fold 0.25/dx^2

    // --- Phase A: stage T_prev, rows clamped in y; vector loads unless the
    //     float4 spans an x edge (only x-edge blocks take the scalar path) ---
    for (int idx = tid; idx < RA * CA4; idx += 256) {
        int j  = idx / CA4;
        int cc = idx - j * CA4;
        int gy  = min(max(y0 + j - 2, 0), NH - 1);
        int gxb = x0 - 4 + 4 * cc;
        float4 t4;
        if (gxb >= 0 && gxb + 3 < NW) {
            t4 = *(const float4*)&Tc[(size_t)gy * NW + gxb];
        } else {
            float* f = (float*)&t4;
            #pragma unroll
            for (int k = 0; k < 4; k++) {
                int cgx = min(max(gxb + k, 0), NW - 1);
                f[k] = Tc[(size_t)gy * NW + cgx];
            }
        }
        *(float4*)&sT[j * STW + 4 * cc] = t4;
    }
    __syncthreads();

    // --- Phase B: T_new on halo-1 grid (plus junk cols at the far pads,
    //     never read by Phase C). Halo points recomputed at CLAMPED coords
    //     -> correct edge replication of T_new.
    //     Interior path: 5 aligned b128 LDS reads (center, x-4, x+4, y-1, y+1)
    //     replace 20 scalar reads. Junk from the pad float4s (s[-4].w at
    //     cc=0, s[+4].x at cc=33) only reaches outputs Phase C never reads
    //     (positions 0..2 and 133..135). ---
    for (int idx = tid; idx < RB * CA4; idx += 256) {
        int ty = idx / CA4;
        int cc = idx - ty * CA4;
        int gy  = y0 + ty - 1;
        int cgy = min(max(gy, 0), NH - 1);
        int lj  = cgy - y0 + 2;              // in [1, RA-2]
        int gxb = x0 - 4 + 4 * cc;
        size_t rowo = (size_t)cgy * NW;
        float tn[4];
        if (gxb >= 0 && gxb + 3 < NW) {
            float4 u4 = *(const float4*)&Uc[rowo + gxb];
            float4 v4 = *(const float4*)&Vc[rowo + gxb];
            const float* s = &sT[lj * STW + 4 * cc];
            float4 cm = *(const float4*)(s - 4);     // only .w (= s[-1]) used
            float4 c4 = *(const float4*)(s);
            float4 cp = *(const float4*)(s + 4);     // only .x (= s[4]) used
            float4 up = *(const float4*)(s - STW);
            float4 dn = *(const float4*)(s + STW);
            float cx[6] = {cm.w, c4.x, c4.y, c4.z, c4.w, cp.x};
            float uu[4] = {u4.x, u4.y, u4.z, u4.w};
            float vv[4] = {v4.x, v4.y, v4.z, v4.w};
            float uq[4] = {up.x, up.y, up.z, up.w};
            float dq[4] = {dn.x, dn.y, dn.z, dn.w};
            #pragma unroll
            for (int k = 0; k < 4; k++) {
                float c = cx[k + 1];
                float selx = (uu[k] > 0.f) ? (c - cx[k])
                           : ((uu[k] < 0.f) ? (cx[k + 2] - c) : 0.f);
                float sely = (vv[k] > 0.f) ? (c - uq[k])
                           : ((vv[k] < 0.f) ? (dq[k] - c) : 0.f);
                tn[k] = c - dt_dx * (uu[k] * selx + vv[k] * sely);
            }
        } else {
            // scalar clamped path: only the two x-edge block columns take this
            #pragma unroll
            for (int k = 0; k < 4; k++) {
                int cgx = min(max(gxb + k, 0), NW - 1);
                float uu = Uc[rowo + cgx];
                float vv = Vc[rowo + cgx];
                int li = cgx - x0 + 4;       // index LDS by clamped coord
                const float* s = &sT[lj * STW + li];
                float c = s[0];
                float selx = (uu > 0.f) ? (c - s[-1])
                           : ((uu < 0.f) ? (s[1] - c) : 0.f);
                float sely = (vv > 0.f) ? (c - s[-STW])
                           : ((vv < 0.f) ? (s[STW] - c) : 0.f);
                tn[k] = c - dt_dx * (uu * selx + vv * sely);
            }
        }
        *(float4*)&sN[ty * SNW + 4 * cc] = make_float4(tn[0], tn[1], tn[2], tn[3]);
    }
    __syncthreads();

    // --- Phase C: 9-pt Laplacian of T_new + source, aligned float4 I/O.
    //     9 aligned b128 LDS reads (3 rows x {x-4, x, x+4}); m*.w / p*.x are
    //     the +-1 neighbors. ---
    float* Ob = out + b * cs;
    for (int idx = tid; idx < TY * (TX / 4); idx += 256) {
        int ty = idx / (TX / 4);
        int cc = idx - ty * (TX / 4);
        int gy  = y0 + ty;
        int gxb = x0 + 4 * cc;
        const float* r0 = &sN[ty * SNW + 4 + 4 * cc];   // row gy-1
        const float* r1 = r0 + SNW;                     // row gy
        const float* r2 = r1 + SNW;                     // row gy+1
        float4 rq = *(const float4*)&Rc[(size_t)gy * NW + gxb];
        float4 m0 = *(const float4*)(r0 - 4);
        float4 a0 = *(const float4*)(r0);
        float4 p0 = *(const float4*)(r0 + 4);
        float4 m1 = *(const float4*)(r1 - 4);
        float4 a1 = *(const float4*)(r1);
        float4 p1 = *(const float4*)(r1 + 4);
        float4 m2 = *(const float4*)(r2 - 4);
        float4 a2 = *(const float4*)(r2);
        float4 p2 = *(const float4*)(r2 + 4);
        float X0[6] = {m0.w, a0.x, a0.y, a0.z, a0.w, p0.x};
        float X1[6] = {m1.w, a1.x, a1.y, a1.z, a1.w, p1.x};
        float X2[6] = {m2.w, a2.x, a2.y, a2.z, a2.w, p2.x};
        float rqv[4] = {rq.x, rq.y, rq.z, rq.w};
        float o[4];
        #pragma unroll
        for (int k = 0; k < 4; k++) {
            float lap = (        X0[k] + 2.f * X0[k + 1] +        X0[k + 2]
                        + 2.f * X1[k] - 12.f * X1[k + 1] + 2.f * X1[k + 2]
                        +       X2[k] + 2.f * X2[k + 1] +        X2[k + 2]) * q_dx2;
            o[k] = X1[k + 1] + dt * (lap + rqv[k]);
        }
        *(float4*)&Ob[(size_t)gy * NW + gxb] = make_float4(o[0], o[1], o[2], o[3]);
    }

    // dt scalar (last output element)
    if (b == 0 && blockIdx.x == 0 && blockIdx.y == 0 && tid == 0)
        out[(size_t)NB * cs] = dt;
}

extern "C" void kernel_launch(void* const* d_in, const int* in_sizes, int n_in,
                              void* d_out, int out_size, void* d_ws, size_t ws_size,
                              hipStream_t stream) {
    const float* in = (const float*)d_in[0];
    float* out = (float*)d_out;
    float* part = (float*)d_ws;   // NPART floats, fully overwritten each call

    uvmax_kernel<<<NPART, 256, 0, stream>>>((const float4*)in, part);

    dim3 grid(NW / TX, NH / TY, NB);   // (8, 64, 16)
    step_kernel<<<grid, 256, 0, stream>>>(in, part, out);
}